// Round 6
// baseline (1120.969 us; speedup 1.0000x reference)
//
#include <hip/hip_runtime.h>
#include <math.h>

// B=64, I=K=2048, H=N=2048, T=128.  m = b*128 + t (M=8192).
// Numerics contract (VALIDATED GREEN): Eigen gebp kc=320 K-panels; per C
// element an ascending-k FMA chain within each 320-panel (register
// accumulator), panels combined by UNFUSED f32 adds (beta=0 first).
// w_eff = __fmul_rn(weight, strength) rounded once. Scan: f32 state,
// unfused mul/add; exact batch mean via ballot/popcount; correctly-rounded
// expf via (float)exp((double)quotient).
//
// R6 = R1's measured-791us structure (8x8 per-thread tile, A-DMA staging,
// proven full-line C stores) with ONE change: B comes straight from global
// (L2/L3-resident weff) via a depth-4 register pipeline instead of LDS.
// LDS delivery halves (64->32 B per thread-k) -> FMA-bound; LDS 64->32 KiB
// raises occupancy. B values and FMA chain order are bit-identical.

#define KT 32

__device__ __forceinline__ void async_copy16(const float* g, float* l) {
    __builtin_amdgcn_global_load_lds(
        (const __attribute__((address_space(1))) void*)g,
        (__attribute__((address_space(3))) void*)l, 16, 0, 0);
}

// weff[i][hl] = __fmul_rn(weight[i][h_base+hl], strength[i][h_base+hl])
__global__ __launch_bounds__(256) void weff_kernel(
    const float* __restrict__ weight, const float* __restrict__ strength,
    float* __restrict__ weff, int h_base, int Hc)
{
    const int i = blockIdx.x;  // input row 0..2047
    const float* wr = weight   + (size_t)i * 2048 + h_base;
    const float* sr = strength + (size_t)i * 2048 + h_base;
    float* dr = weff + (size_t)i * Hc;
    for (int c = threadIdx.x * 4; c < Hc; c += 1024) {
        float4 wv = *(const float4*)&wr[c];
        float4 sv = *(const float4*)&sr[c];
        float4 o;
        o.x = __fmul_rn(wv.x, sv.x);
        o.y = __fmul_rn(wv.y, sv.y);
        o.z = __fmul_rn(wv.z, sv.z);
        o.w = __fmul_rn(wv.w, sv.w);
        *(float4*)&dr[c] = o;
    }
}

__global__ __launch_bounds__(256, 2) void gemm_kernel(
    const float* __restrict__ spikes,  // [64][2048][128]
    const float* __restrict__ weff,    // [2048][Hc]
    float* __restrict__ Ct,            // [Hc][M=8192]
    int Hc)
{
    __shared__ __align__(16) float A_lds[2][KT][128];  // 32 KiB (A only)

    const int tid  = threadIdx.x;
    const int w    = tid >> 6;         // wave
    const int lane = tid & 63;
    const int bx   = blockIdx.x;       // h-tile within chunk
    const int by   = blockIdx.y;       // batch b
    const int h0l  = bx * 128;
    const int m0   = by * 128;
    const int tx   = tid & 15;
    const int ty   = tid >> 4;

    float acc[8][8];   // current 320-panel accumulator (ascending-k chain)
    float tot[8][8];   // running unfused panel total
#pragma unroll
    for (int i = 0; i < 8; i++)
#pragma unroll
        for (int j = 0; j < 8; j++) { acc[i][j] = 0.0f; tot[i][j] = 0.0f; }

    const float* a_base = spikes + (size_t)by * 262144;  // b * I * T

    // A staging (R1's proven DMA): tile = 16 KiB contiguous global; wave w
    // covers its 4-KiB quarter with 4 instrs. Wave-uniform LDS dest.
    auto stageA = [&](int buf, int kt) {
        const int k0 = kt * KT;
        const float* asrc = a_base + ((size_t)k0 << 7) + (w << 10) + (lane << 2);
        float* adst = &A_lds[buf][0][0] + (w << 10);
#pragma unroll
        for (int i = 0; i < 4; i++)
            async_copy16(asrc + (i << 8), adst + (i << 8));
    };

    // B register pipeline, depth 4. wrow is a UNIFORM row pointer (k-row),
    // boff the per-lane constant column offset -> s[base]+v_off codegen.
    // Same weff element values, consumed at the same chain positions.
    const float* wrow = weff + h0l;    // k = 0
    const int boff = 4 * tx;
    float4 bpf[4][2];
#pragma unroll
    for (int p = 0; p < 4; p++) {
        bpf[p][0] = *(const float4*)&wrow[boff];
        bpf[p][1] = *(const float4*)&wrow[boff + 64];
        wrow += Hc;
    }                                   // wrow -> k = 4

    stageA(0, 0);
    __syncthreads();   // prologue drain (only exposed DMA latency)

    int cur = 0;
    for (int kt = 0; kt < 64; kt++) {
        if (kt < 63) stageA(cur ^ 1, kt + 1);   // issue A-DMA, no wait

#pragma unroll
        for (int kk = 0; kk < KT; kk++) {
            const int k = kt * KT + kk;
            const float4 a0 = *(const float4*)&A_lds[cur][kk][4 * ty];
            const float4 a1 = *(const float4*)&A_lds[cur][kk][4 * ty + 64];
            const float4 b0 = bpf[kk & 3][0];
            const float4 b1 = bpf[kk & 3][1];
            // refill slot with row k+4 (clamped at 2047; clamped loads are
            // in-bounds and never consumed)
            bpf[kk & 3][0] = *(const float4*)&wrow[boff];
            bpf[kk & 3][1] = *(const float4*)&wrow[boff + 64];
            if (k + 4 < 2047) wrow += Hc;       // uniform advance
            float a[8] = {a0.x, a0.y, a0.z, a0.w, a1.x, a1.y, a1.z, a1.w};
            float b[8] = {b0.x, b0.y, b0.z, b0.w, b1.x, b1.y, b1.z, b1.w};
#pragma unroll
            for (int i = 0; i < 8; i++)
#pragma unroll
                for (int j = 0; j < 8; j++)
                    acc[i][j] = __builtin_fmaf(a[i], b[j], acc[i][j]);
        }

        // Eigen kc=320 panel boundary: unfused fold into total, reset chain
        if (((kt + 1) % 10 == 0) || (kt == 63)) {
#pragma unroll
            for (int i = 0; i < 8; i++)
#pragma unroll
                for (int j = 0; j < 8; j++) {
                    tot[i][j] = __fadd_rn(tot[i][j], acc[i][j]);
                    acc[i][j] = 0.0f;
                }
        }

        __syncthreads();   // drains A-DMA (landed under compute) + fences
        cur ^= 1;          // buffer reuse
    }

    // R1 epilogue verbatim: per instruction, 4 consecutive-ty lanes form
    // one full 64-B line per row -> no partial-line writes (WRITE=65 MB).
#pragma unroll
    for (int j = 0; j < 8; j++) {
        const int hl = h0l + 4 * tx + (j & 3) + ((j >> 2) << 6);
        float4 v0 = make_float4(tot[0][j], tot[1][j], tot[2][j], tot[3][j]);
        float4 v1 = make_float4(tot[4][j], tot[5][j], tot[6][j], tot[7][j]);
        *(float4*)&Ct[(size_t)hl * 8192 + m0 + 4 * ty]      = v0;
        *(float4*)&Ct[(size_t)hl * 8192 + m0 + 4 * ty + 64] = v1;
    }
}

// One wave (64 lanes) per h; lane = batch b. Scan state f32, unfused.
// Batch-mean via ballot/popcount (exact). Validated numerics — UNCHANGED
// (verbatim R1 version; Wt layout [Hc][B][T] = [Hc][8192]).
__global__ __launch_bounds__(256) void scan_kernel(
    const float* __restrict__ Wt,          // [Hc][B][T] f32 chunk-local
    const float* __restrict__ threshold,   // [H] f32 global
    const float* __restrict__ p_tau_mem,
    const float* __restrict__ p_tau_syn,
    const float* __restrict__ p_target,
    const float* __restrict__ p_lr,
    float* __restrict__ out,               // [B][H][T] f32 global
    int h_base)
{
    __shared__ float S[4 * 64 * 17];
    __shared__ unsigned int Bits[4][64][4];

    const int tid  = threadIdx.x;
    const int w    = tid >> 6;
    const int lane = tid & 63;            // batch b
    const int hl   = blockIdx.x * 4 + w;  // chunk-local h

    const float tau_mem = p_tau_mem[0];
    const float tau_syn = p_tau_syn[0];
    const float target  = p_target[0];
    const float lr      = p_lr[0];
    const float a_mem = (float)exp((double)__fdiv_rn(-0.001f, tau_mem));
    const float a_syn = (float)exp((double)__fdiv_rn(-0.001f, tau_syn));

    float i_syn = 0.0f, v_mem = 0.0f;
    float thr = threshold[h_base + hl];
    float fre = 0.0f;
    unsigned int bits[4] = {0u, 0u, 0u, 0u};

    const int st4 = tid & 3;
    const int sb  = (tid >> 2) & 63;

    for (int tc = 0; tc < 128; tc += 16) {
        __syncthreads();
#pragma unroll
        for (int hh = 0; hh < 4; hh++) {
            const int hg = blockIdx.x * 4 + hh;
            float4 v = *(const float4*)&Wt[(size_t)hg * 8192 + sb * 128 + tc + 4 * st4];
            float* row = &S[(hh * 64 + sb) * 17];
            row[4 * st4 + 0] = v.x;
            row[4 * st4 + 1] = v.y;
            row[4 * st4 + 2] = v.z;
            row[4 * st4 + 3] = v.w;
        }
        __syncthreads();

        const float* row = &S[(w * 64 + lane) * 17];
#pragma unroll
        for (int tt = 0; tt < 16; tt++) {
            const int t = tc + tt;
            const float wv = row[tt];
            i_syn = __fadd_rn(__fmul_rn(a_syn, i_syn), wv);
            v_mem = __fadd_rn(__fmul_rn(a_mem, v_mem), i_syn);
            const bool sp = (v_mem >= thr);
            const unsigned long long mask = __ballot(sp);
            if (sp) v_mem = __fsub_rn(v_mem, thr);
            const int cnt = __popcll(mask);
            const float rate = __fmul_rn((float)cnt, 0.015625f);
            fre = __fadd_rn(__fmul_rn(0.99f, fre), __fmul_rn(0.01f, rate));
            thr = __fadd_rn(thr, __fmul_rn(lr, __fsub_rn(fre, target)));
            if (sp) bits[t >> 5] |= (1u << (t & 31));
        }
    }

    __syncthreads();
    Bits[w][lane][0] = bits[0];
    Bits[w][lane][1] = bits[1];
    Bits[w][lane][2] = bits[2];
    Bits[w][lane][3] = bits[3];
    __syncthreads();

    for (int b = 0; b < 64; b++) {
        const unsigned int word = Bits[w][b][lane >> 4];
        float2 v;
        v.x = ((word >> ((2 * lane) & 31)) & 1u) ? 1.0f : 0.0f;
        v.y = ((word >> ((2 * lane + 1) & 31)) & 1u) ? 1.0f : 0.0f;
        *(float2*)&out[((size_t)b * 2048 + h_base + hl) * 128 + 2 * lane] = v;
    }
}

extern "C" void kernel_launch(void* const* d_in, const int* in_sizes, int n_in,
                              void* d_out, int out_size, void* d_ws, size_t ws_size,
                              hipStream_t stream) {
    const float* spikes    = (const float*)d_in[0];
    const float* weight    = (const float*)d_in[1];
    const float* strength  = (const float*)d_in[2];
    const float* threshold = (const float*)d_in[3];
    const float* tau_mem   = (const float*)d_in[4];
    const float* tau_syn   = (const float*)d_in[5];
    const float* target    = (const float*)d_in[6];
    const float* lr        = (const float*)d_in[7];

    float* out = (float*)d_out;

    // ws holds Wt [Hc][8192] f32 + weff [2048][Hc] f32 = Hc*40960 bytes.
    int Hc = 2048;
    while (Hc > 128 && (size_t)Hc * 40960ull > ws_size) Hc >>= 1;

    float* Wt   = (float*)d_ws;
    float* weff = (float*)d_ws + (size_t)Hc * 8192;

    for (int hb = 0; hb < 2048; hb += Hc) {
        weff_kernel<<<2048, 256, 0, stream>>>(weight, strength, weff, hb, Hc);
        gemm_kernel<<<dim3(Hc / 128, 64), 256, 0, stream>>>(spikes, weff, Wt, Hc);
        scan_kernel<<<Hc / 4, 256, 0, stream>>>(
            Wt, threshold, tau_mem, tau_syn, target, lr, out, hb);
    }
}

// Round 7
// 836.383 us; speedup vs baseline: 1.3403x; 1.3403x over previous
//
#include <hip/hip_runtime.h>
#include <math.h>

// B=64, I=K=2048, H=N=2048, T=128.  m = b*128 + t (M=8192).
// Numerics contract (VALIDATED GREEN): Eigen gebp kc=320 K-panels; per C
// element an ascending-k FMA chain within each 320-panel (register
// accumulator), panels combined by UNFUSED f32 adds (beta=0 first).
// Spikes are EXACT 0.0f/1.0f, so fma(1,b,acc)=__fadd_rn(acc,b) and
// fma(0,b,acc)=acc bit-for-bit (acc=-0 unreachable: acc starts +0 and RN
// sums never yield -0 here) -> skipping zero-spike terms is bit-exact.
// w_eff = __fmul_rn(weight, strength) rounded once. Scan: f32 state,
// unfused mul/add; exact batch mean via ballot/popcount; correctly-rounded
// expf via (float)exp((double)quotient).
//
// R7: sparse GEMM. Wave owns 8 m-rows x 512 h (lanes span h). Spike bits
// pre-packed as bytes bitsT[b][t/8][k]; per k the wave's predicate is ONE
// scalar byte: if(byte)->skip k (P=43%), per-row wave-uniform s_cbranch
// (rows run at true 10% density). LDS b-reads become conditional: 0.57x2
// b128/wave-k (was 4). acc 64 VGPR + tot 64 AGPR (R1-proven shape, no
// spill). Epilogue: LDS transpose (union with dead W buffer), full-line
// 128-B stores per 8-lane group.

__device__ __forceinline__ void async_copy16(const float* g, float* l) {
    __builtin_amdgcn_global_load_lds(
        (const __attribute__((address_space(1))) void*)g,
        (__attribute__((address_space(3))) void*)l, 16, 0, 0);
}

// weff[i][hl] = __fmul_rn(weight[i][h_base+hl], strength[i][h_base+hl])
__global__ __launch_bounds__(256) void weff_kernel(
    const float* __restrict__ weight, const float* __restrict__ strength,
    float* __restrict__ weff, int h_base, int Hc)
{
    const int i = blockIdx.x;  // input row 0..2047
    const float* wr = weight   + (size_t)i * 2048 + h_base;
    const float* sr = strength + (size_t)i * 2048 + h_base;
    float* dr = weff + (size_t)i * Hc;
    for (int c = threadIdx.x * 4; c < Hc; c += 1024) {
        float4 wv = *(const float4*)&wr[c];
        float4 sv = *(const float4*)&sr[c];
        float4 o;
        o.x = __fmul_rn(wv.x, sv.x);
        o.y = __fmul_rn(wv.y, sv.y);
        o.z = __fmul_rn(wv.z, sv.z);
        o.w = __fmul_rn(wv.w, sv.w);
        *(float4*)&dr[c] = o;
    }
}

// bitsT[b][tbyte][k]: bit r = (spikes[b][k][8*tbyte+r] != 0). One wave per
// (b,k): two ballots over 128 t, lanes 0..15 each emit one byte.
__global__ __launch_bounds__(256) void bits_kernel(
    const float* __restrict__ spikes, unsigned char* __restrict__ bitsT)
{
    const int tid  = threadIdx.x;
    const int w    = tid >> 6;
    const int lane = tid & 63;
    const int wid  = blockIdx.x * 4 + w;     // b*2048 + k
    const int b    = wid >> 11;
    const int k    = wid & 2047;
    const float2 v = *(const float2*)&spikes[((size_t)b * 2048 + k) * 128 + 2 * lane];
    const unsigned long long m0 = __ballot(v.x != 0.0f);  // bit l -> t=2l
    const unsigned long long m1 = __ballot(v.y != 0.0f);  // bit l -> t=2l+1
    if (lane < 16) {
        unsigned byte = 0;
#pragma unroll
        for (int q = 0; q < 4; q++) {
            byte |= (unsigned)((m0 >> (4 * lane + q)) & 1ull) << (2 * q);
            byte |= (unsigned)((m1 >> (4 * lane + q)) & 1ull) << (2 * q + 1);
        }
        bitsT[((size_t)b * 16 + lane) * 2048 + k] = (unsigned char)byte;
    }
}

union ShU {
    float Wl[2][16][512];   // 64 KiB: double-buffered weff k-tile
    float Cl[32][516];      // 66 KiB: epilogue transpose tile (+4 pad)
};

__global__ __launch_bounds__(256, 2) void gemm_kernel(
    const float* __restrict__ weff,          // [2048][Hc]
    const unsigned char* __restrict__ bits,  // [64][16][2048]
    float* __restrict__ Ct,                  // [Hc][M=8192]
    int Hc)
{
    __shared__ ShU sh;

    const int tid  = threadIdx.x;
    const int w    = tid >> 6;          // wave 0..3
    const int lane = tid & 63;
    const int h0   = blockIdx.x * 512;  // chunk-local h-tile
    const int mg   = blockIdx.y;        // 0..255: b = mg>>2, t-quarter = mg&3
    const int b    = mg >> 2;
    const int tq   = mg & 3;
    const int m0g  = b * 128 + tq * 32; // block's first m (32 m per block)
    const int wbyte = (tq << 2) + w;    // wave's t-byte (8 m-rows)

    float acc[8][8];   // current 320-panel accumulator (ascending-k chain)
    float tot[8][8];   // running unfused panel total (AGPR-resident)
#pragma unroll
    for (int r = 0; r < 8; r++)
#pragma unroll
        for (int j = 0; j < 8; j++) { acc[r][j] = 0.0f; tot[r][j] = 0.0f; }

    const unsigned char* bp = bits + (((size_t)b * 16 + wbyte) << 11);

    // Stage k-tile kt (16 rows x 512 cols = 32 KiB) into buffer buf.
    // Wave w covers rows 4w..4w+3, 2 KiB each as 2 DMA halves.
    auto stageW = [&](int buf, int kt) {
        const int k0 = kt << 4;
        const int r  = w << 2;
#pragma unroll
        for (int i = 0; i < 4; i++) {
            const float* src = &weff[(size_t)(k0 + r + i) * Hc + h0 + (lane << 2)];
            async_copy16(src,       &sh.Wl[buf][r + i][0]);
            async_copy16(src + 256, &sh.Wl[buf][r + i][256]);
        }
    };

#define ROWADD(r) { \
        acc[r][0] = __fadd_rn(acc[r][0], b0.x); \
        acc[r][1] = __fadd_rn(acc[r][1], b0.y); \
        acc[r][2] = __fadd_rn(acc[r][2], b0.z); \
        acc[r][3] = __fadd_rn(acc[r][3], b0.w); \
        acc[r][4] = __fadd_rn(acc[r][4], b1.x); \
        acc[r][5] = __fadd_rn(acc[r][5], b1.y); \
        acc[r][6] = __fadd_rn(acc[r][6], b1.z); \
        acc[r][7] = __fadd_rn(acc[r][7], b1.w); }

    uint4 pkv = *(const uint4*)bp;        // bytes for k-tile 0
    stageW(0, 0);
    __syncthreads();                      // prologue drain

    int cur = 0;
    for (int kt = 0; kt < 128; kt++) {
        uint4 pknx = pkv;
        if (kt < 127) {
            stageW(cur ^ 1, kt + 1);      // issue DMA, no wait
            pknx = *(const uint4*)(bp + ((kt + 1) << 4));
        }
        // Force the wave-shared spike bytes into SGPRs -> uniform branches.
        const unsigned w0 = __builtin_amdgcn_readfirstlane(pkv.x);
        const unsigned w1 = __builtin_amdgcn_readfirstlane(pkv.y);
        const unsigned w2 = __builtin_amdgcn_readfirstlane(pkv.z);
        const unsigned w3 = __builtin_amdgcn_readfirstlane(pkv.w);

#pragma unroll
        for (int kk = 0; kk < 16; kk++) {
            const unsigned word =
                (kk < 4) ? w0 : (kk < 8) ? w1 : (kk < 12) ? w2 : w3;
            const unsigned byte = (word >> ((kk & 3) * 8)) & 0xFFu;
            if (byte) {                   // uniform: skip k entirely if no
                const float4 b0 =         // spike in this wave's 8 m-rows
                    *(const float4*)&sh.Wl[cur][kk][lane << 2];
                const float4 b1 =
                    *(const float4*)&sh.Wl[cur][kk][(lane << 2) + 256];
                if (byte & 1u)   ROWADD(0)
                if (byte & 2u)   ROWADD(1)
                if (byte & 4u)   ROWADD(2)
                if (byte & 8u)   ROWADD(3)
                if (byte & 16u)  ROWADD(4)
                if (byte & 32u)  ROWADD(5)
                if (byte & 64u)  ROWADD(6)
                if (byte & 128u) ROWADD(7)
            }
        }

        // Eigen kc=320 panel boundary (320 = 20 tiles of 16; tail 128):
        // unfused fold into total, reset chain.
        if (((kt + 1) % 20 == 0) || (kt == 127)) {
#pragma unroll
            for (int r = 0; r < 8; r++)
#pragma unroll
                for (int j = 0; j < 8; j++) {
                    tot[r][j] = __fadd_rn(tot[r][j], acc[r][j]);
                    acc[r][j] = 0.0f;
                }
        }

        __syncthreads();   // drains next-tile DMA (landed under compute)
        pkv = pknx;
        cur ^= 1;
    }

    // ---- Epilogue: transpose via LDS (W buffers dead), full-line stores ----
    // Write: thread's 8 m-rows x 8 h into Cl[m][h] (b128, h-contiguous).
#pragma unroll
    for (int r = 0; r < 8; r++) {
        const int ml = (w << 3) + r;
        *(float4*)&sh.Cl[ml][lane << 2] =
            make_float4(tot[r][0], tot[r][1], tot[r][2], tot[r][3]);
        *(float4*)&sh.Cl[ml][(lane << 2) + 256] =
            make_float4(tot[r][4], tot[r][5], tot[r][6], tot[r][7]);
    }
    __syncthreads();
    // Read + store: per instruction 32 h-rows x 32 m; each 8-lane group
    // writes one 128-B line-aligned segment of a Ct row.
#pragma unroll
    for (int u = 0; u < 16; u++) {
        const int hr = (u << 5) + (tid >> 3);
        const int mq = (tid & 7) << 2;
        float4 v;
        v.x = sh.Cl[mq + 0][hr];
        v.y = sh.Cl[mq + 1][hr];
        v.z = sh.Cl[mq + 2][hr];
        v.w = sh.Cl[mq + 3][hr];
        *(float4*)&Ct[(size_t)(h0 + hr) * 8192 + m0g + mq] = v;
    }
#undef ROWADD
}

// One wave (64 lanes) per h; lane = batch b. Scan state f32, unfused.
// Batch-mean via ballot/popcount (exact). Validated numerics — UNCHANGED
// (verbatim R1 version; Wt layout [Hc][B][T] = [Hc][8192]).
__global__ __launch_bounds__(256) void scan_kernel(
    const float* __restrict__ Wt,          // [Hc][B][T] f32 chunk-local
    const float* __restrict__ threshold,   // [H] f32 global
    const float* __restrict__ p_tau_mem,
    const float* __restrict__ p_tau_syn,
    const float* __restrict__ p_target,
    const float* __restrict__ p_lr,
    float* __restrict__ out,               // [B][H][T] f32 global
    int h_base)
{
    __shared__ float S[4 * 64 * 17];
    __shared__ unsigned int Bits[4][64][4];

    const int tid  = threadIdx.x;
    const int w    = tid >> 6;
    const int lane = tid & 63;            // batch b
    const int hl   = blockIdx.x * 4 + w;  // chunk-local h

    const float tau_mem = p_tau_mem[0];
    const float tau_syn = p_tau_syn[0];
    const float target  = p_target[0];
    const float lr      = p_lr[0];
    const float a_mem = (float)exp((double)__fdiv_rn(-0.001f, tau_mem));
    const float a_syn = (float)exp((double)__fdiv_rn(-0.001f, tau_syn));

    float i_syn = 0.0f, v_mem = 0.0f;
    float thr = threshold[h_base + hl];
    float fre = 0.0f;
    unsigned int bits[4] = {0u, 0u, 0u, 0u};

    const int st4 = tid & 3;
    const int sb  = (tid >> 2) & 63;

    for (int tc = 0; tc < 128; tc += 16) {
        __syncthreads();
#pragma unroll
        for (int hh = 0; hh < 4; hh++) {
            const int hg = blockIdx.x * 4 + hh;
            float4 v = *(const float4*)&Wt[(size_t)hg * 8192 + sb * 128 + tc + 4 * st4];
            float* row = &S[(hh * 64 + sb) * 17];
            row[4 * st4 + 0] = v.x;
            row[4 * st4 + 1] = v.y;
            row[4 * st4 + 2] = v.z;
            row[4 * st4 + 3] = v.w;
        }
        __syncthreads();

        const float* row = &S[(w * 64 + lane) * 17];
#pragma unroll
        for (int tt = 0; tt < 16; tt++) {
            const int t = tc + tt;
            const float wv = row[tt];
            i_syn = __fadd_rn(__fmul_rn(a_syn, i_syn), wv);
            v_mem = __fadd_rn(__fmul_rn(a_mem, v_mem), i_syn);
            const bool sp = (v_mem >= thr);
            const unsigned long long mask = __ballot(sp);
            if (sp) v_mem = __fsub_rn(v_mem, thr);
            const int cnt = __popcll(mask);
            const float rate = __fmul_rn((float)cnt, 0.015625f);
            fre = __fadd_rn(__fmul_rn(0.99f, fre), __fmul_rn(0.01f, rate));
            thr = __fadd_rn(thr, __fmul_rn(lr, __fsub_rn(fre, target)));
            if (sp) bits[t >> 5] |= (1u << (t & 31));
        }
    }

    __syncthreads();
    Bits[w][lane][0] = bits[0];
    Bits[w][lane][1] = bits[1];
    Bits[w][lane][2] = bits[2];
    Bits[w][lane][3] = bits[3];
    __syncthreads();

    for (int b = 0; b < 64; b++) {
        const unsigned int word = Bits[w][b][lane >> 4];
        float2 v;
        v.x = ((word >> ((2 * lane) & 31)) & 1u) ? 1.0f : 0.0f;
        v.y = ((word >> ((2 * lane + 1) & 31)) & 1u) ? 1.0f : 0.0f;
        *(float2*)&out[((size_t)b * 2048 + h_base + hl) * 128 + 2 * lane] = v;
    }
}

extern "C" void kernel_launch(void* const* d_in, const int* in_sizes, int n_in,
                              void* d_out, int out_size, void* d_ws, size_t ws_size,
                              hipStream_t stream) {
    const float* spikes    = (const float*)d_in[0];
    const float* weight    = (const float*)d_in[1];
    const float* strength  = (const float*)d_in[2];
    const float* threshold = (const float*)d_in[3];
    const float* tau_mem   = (const float*)d_in[4];
    const float* tau_syn   = (const float*)d_in[5];
    const float* target    = (const float*)d_in[6];
    const float* lr        = (const float*)d_in[7];

    float* out = (float*)d_out;

    // ws: Wt [Hc][8192] f32 + weff [2048][Hc] f32 + bitsT 2 MiB.
    int Hc = 2048;
    while (Hc > 512 && (size_t)Hc * 40960ull + 2097152ull > ws_size) Hc >>= 1;

    float* Wt   = (float*)d_ws;
    float* weff = (float*)d_ws + (size_t)Hc * 8192;
    unsigned char* bitsT = (unsigned char*)(weff + (size_t)2048 * Hc);

    bits_kernel<<<32768, 256, 0, stream>>>(spikes, bitsT);

    for (int hb = 0; hb < 2048; hb += Hc) {
        weff_kernel<<<2048, 256, 0, stream>>>(weight, strength, weff, hb, Hc);
        gemm_kernel<<<dim3(Hc / 512, 256), 256, 0, stream>>>(weff, bitsT, Wt, Hc);
        scan_kernel<<<Hc / 4, 256, 0, stream>>>(
            Wt, threshold, tau_mem, tau_syn, target, lr, out, hb);
    }
}

// Round 8
// 717.706 us; speedup vs baseline: 1.5619x; 1.1654x over previous
//
#include <hip/hip_runtime.h>
#include <math.h>

// B=64, I=K=2048, H=N=2048, T=128.  m = b*128 + t (M=8192).
// Numerics contract (VALIDATED GREEN): Eigen gebp kc=320 K-panels; per C
// element an ascending-k FMA chain within each 320-panel (register
// accumulator), panels combined by UNFUSED f32 adds (beta=0 first).
// Spikes are EXACT 0.0f/1.0f, so fma(1,b,acc)=__fadd_rn(acc,b) and
// fma(0,b,acc)=acc bit-for-bit -> skipping zero-spike terms is bit-exact.
// w_eff = __fmul_rn(weight, strength) rounded once. Scan: f32 state,
// unfused mul/add; exact batch mean via ballot/popcount; correctly-rounded
// expf via (float)exp((double)quotient).
//
// R8 = R7 with the B-read de-conflicted. R7's ds_read_b128 (64 lanes x
// contiguous 16-B units) is a structural 8-way bank conflict (per pass,
// banks (4i+p)%32 span only 8 banks) -> 2.3e8 conflict cycles = ~380us.
// Fix: lane i reads h = 64*j + lane (stride-64 words, 8x ds_read_b32,
// immediate offsets): 64 consecutive words/instr -> 2-way -> free.
// acc[r][j] now tracks h = j*64+lane; epilogue transpose adjusted.
// Per-(m,h) add-chain order unchanged -> bit-exact.

__device__ __forceinline__ void async_copy16(const float* g, float* l) {
    __builtin_amdgcn_global_load_lds(
        (const __attribute__((address_space(1))) void*)g,
        (__attribute__((address_space(3))) void*)l, 16, 0, 0);
}

// weff[i][hl] = __fmul_rn(weight[i][h_base+hl], strength[i][h_base+hl])
__global__ __launch_bounds__(256) void weff_kernel(
    const float* __restrict__ weight, const float* __restrict__ strength,
    float* __restrict__ weff, int h_base, int Hc)
{
    const int i = blockIdx.x;  // input row 0..2047
    const float* wr = weight   + (size_t)i * 2048 + h_base;
    const float* sr = strength + (size_t)i * 2048 + h_base;
    float* dr = weff + (size_t)i * Hc;
    for (int c = threadIdx.x * 4; c < Hc; c += 1024) {
        float4 wv = *(const float4*)&wr[c];
        float4 sv = *(const float4*)&sr[c];
        float4 o;
        o.x = __fmul_rn(wv.x, sv.x);
        o.y = __fmul_rn(wv.y, sv.y);
        o.z = __fmul_rn(wv.z, sv.z);
        o.w = __fmul_rn(wv.w, sv.w);
        *(float4*)&dr[c] = o;
    }
}

// bitsT[b][tbyte][k]: bit r = (spikes[b][k][8*tbyte+r] != 0). One wave per
// (b,k): two ballots over 128 t, lanes 0..15 each emit one byte.
__global__ __launch_bounds__(256) void bits_kernel(
    const float* __restrict__ spikes, unsigned char* __restrict__ bitsT)
{
    const int tid  = threadIdx.x;
    const int w    = tid >> 6;
    const int lane = tid & 63;
    const int wid  = blockIdx.x * 4 + w;     // b*2048 + k
    const int b    = wid >> 11;
    const int k    = wid & 2047;
    const float2 v = *(const float2*)&spikes[((size_t)b * 2048 + k) * 128 + 2 * lane];
    const unsigned long long m0 = __ballot(v.x != 0.0f);  // bit l -> t=2l
    const unsigned long long m1 = __ballot(v.y != 0.0f);  // bit l -> t=2l+1
    if (lane < 16) {
        unsigned byte = 0;
#pragma unroll
        for (int q = 0; q < 4; q++) {
            byte |= (unsigned)((m0 >> (4 * lane + q)) & 1ull) << (2 * q);
            byte |= (unsigned)((m1 >> (4 * lane + q)) & 1ull) << (2 * q + 1);
        }
        bitsT[((size_t)b * 16 + lane) * 2048 + k] = (unsigned char)byte;
    }
}

union ShU {
    float Wl[2][16][512];   // 64 KiB: double-buffered weff k-tile
    float Cl[32][517];      // 66.2 KiB: epilogue transpose (517: bank-spread)
};

__global__ __launch_bounds__(256, 2) void gemm_kernel(
    const float* __restrict__ weff,          // [2048][Hc]
    const unsigned char* __restrict__ bits,  // [64][16][2048]
    float* __restrict__ Ct,                  // [Hc][M=8192]
    int Hc)
{
    __shared__ ShU sh;

    const int tid  = threadIdx.x;
    const int w    = tid >> 6;          // wave 0..3
    const int lane = tid & 63;
    const int h0   = blockIdx.x * 512;  // chunk-local h-tile
    const int mg   = blockIdx.y;        // 0..255: b = mg>>2, t-quarter = mg&3
    const int b    = mg >> 2;
    const int tq   = mg & 3;
    const int m0g  = b * 128 + tq * 32; // block's first m (32 m per block)
    const int wbyte = (tq << 2) + w;    // wave's t-byte (8 m-rows)

    float acc[8][8];   // acc[r][j]: m-row r, h = h0 + 64*j + lane
    float tot[8][8];   // running unfused panel total (AGPR-resident)
#pragma unroll
    for (int r = 0; r < 8; r++)
#pragma unroll
        for (int j = 0; j < 8; j++) { acc[r][j] = 0.0f; tot[r][j] = 0.0f; }

    const unsigned char* bp = bits + (((size_t)b * 16 + wbyte) << 11);

    // Stage k-tile kt (16 rows x 512 cols = 32 KiB) into buffer buf.
    // Wave w covers rows 4w..4w+3, 2 KiB each as 2 DMA halves.
    auto stageW = [&](int buf, int kt) {
        const int k0 = kt << 4;
        const int r  = w << 2;
#pragma unroll
        for (int i = 0; i < 4; i++) {
            const float* src = &weff[(size_t)(k0 + r + i) * Hc + h0 + (lane << 2)];
            async_copy16(src,       &sh.Wl[buf][r + i][0]);
            async_copy16(src + 256, &sh.Wl[buf][r + i][256]);
        }
    };

#define ROWADD(r) { \
        acc[r][0] = __fadd_rn(acc[r][0], bf[0]); \
        acc[r][1] = __fadd_rn(acc[r][1], bf[1]); \
        acc[r][2] = __fadd_rn(acc[r][2], bf[2]); \
        acc[r][3] = __fadd_rn(acc[r][3], bf[3]); \
        acc[r][4] = __fadd_rn(acc[r][4], bf[4]); \
        acc[r][5] = __fadd_rn(acc[r][5], bf[5]); \
        acc[r][6] = __fadd_rn(acc[r][6], bf[6]); \
        acc[r][7] = __fadd_rn(acc[r][7], bf[7]); }

    uint4 pkv = *(const uint4*)bp;        // bytes for k-tile 0
    stageW(0, 0);
    __syncthreads();                      // prologue drain

    int cur = 0;
    for (int kt = 0; kt < 128; kt++) {
        uint4 pknx = pkv;
        if (kt < 127) {
            stageW(cur ^ 1, kt + 1);      // issue DMA, no wait
            pknx = *(const uint4*)(bp + ((kt + 1) << 4));
        }
        // Force the wave-shared spike bytes into SGPRs -> uniform branches.
        const unsigned w0 = __builtin_amdgcn_readfirstlane(pkv.x);
        const unsigned w1 = __builtin_amdgcn_readfirstlane(pkv.y);
        const unsigned w2 = __builtin_amdgcn_readfirstlane(pkv.z);
        const unsigned w3 = __builtin_amdgcn_readfirstlane(pkv.w);

        // Per-lane base into the current buffer; all read offsets below are
        // compile-time immediates (kk*2048 + j*256 bytes <= 32512).
        const float* wrow = &sh.Wl[cur][0][0] + lane;

#pragma unroll
        for (int kk = 0; kk < 16; kk++) {
            const unsigned word =
                (kk < 4) ? w0 : (kk < 8) ? w1 : (kk < 12) ? w2 : w3;
            const unsigned byte = (word >> ((kk & 3) * 8)) & 0xFFu;
            if (byte) {                   // uniform: skip k entirely if no
                float bf[8];              // spike in this wave's 8 m-rows
#pragma unroll
                for (int j = 0; j < 8; j++)
                    bf[j] = wrow[kk * 512 + j * 64];  // 64 consec words: free
                if (byte & 1u)   ROWADD(0)
                if (byte & 2u)   ROWADD(1)
                if (byte & 4u)   ROWADD(2)
                if (byte & 8u)   ROWADD(3)
                if (byte & 16u)  ROWADD(4)
                if (byte & 32u)  ROWADD(5)
                if (byte & 64u)  ROWADD(6)
                if (byte & 128u) ROWADD(7)
            }
        }

        // Eigen kc=320 panel boundary (320 = 20 tiles of 16; tail 128):
        // unfused fold into total, reset chain.
        if (((kt + 1) % 20 == 0) || (kt == 127)) {
#pragma unroll
            for (int r = 0; r < 8; r++)
#pragma unroll
                for (int j = 0; j < 8; j++) {
                    tot[r][j] = __fadd_rn(tot[r][j], acc[r][j]);
                    acc[r][j] = 0.0f;
                }
        }

        __syncthreads();   // drains next-tile DMA (landed under compute)
        pkv = pknx;
        cur ^= 1;
    }

    // ---- Epilogue: transpose via LDS (W buffers dead), full-line stores ----
    // Write: tot[r][j] is (m = w*8+r, h = j*64+lane); stride-1 word writes
    // (64 consec words per instr -> 2-way free; row stride 517 spreads rows).
#pragma unroll
    for (int r = 0; r < 8; r++) {
        const int ml = (w << 3) + r;
#pragma unroll
        for (int j = 0; j < 8; j++)
            sh.Cl[ml][j * 64 + lane] = tot[r][j];
    }
    __syncthreads();
    // Read + store: per instruction 32 h-rows x 32 m; each 8-lane group
    // writes one 128-B line-aligned segment of a Ct row.
#pragma unroll
    for (int u = 0; u < 16; u++) {
        const int hr = (u << 5) + (tid >> 3);
        const int mq = (tid & 7) << 2;
        float4 v;
        v.x = sh.Cl[mq + 0][hr];
        v.y = sh.Cl[mq + 1][hr];
        v.z = sh.Cl[mq + 2][hr];
        v.w = sh.Cl[mq + 3][hr];
        *(float4*)&Ct[(size_t)(h0 + hr) * 8192 + m0g + mq] = v;
    }
#undef ROWADD
}

// One wave (64 lanes) per h; lane = batch b. Scan state f32, unfused.
// Batch-mean via ballot/popcount (exact). Validated numerics — UNCHANGED
// (verbatim R1 version; Wt layout [Hc][B][T] = [Hc][8192]).
__global__ __launch_bounds__(256) void scan_kernel(
    const float* __restrict__ Wt,          // [Hc][B][T] f32 chunk-local
    const float* __restrict__ threshold,   // [H] f32 global
    const float* __restrict__ p_tau_mem,
    const float* __restrict__ p_tau_syn,
    const float* __restrict__ p_target,
    const float* __restrict__ p_lr,
    float* __restrict__ out,               // [B][H][T] f32 global
    int h_base)
{
    __shared__ float S[4 * 64 * 17];
    __shared__ unsigned int Bits[4][64][4];

    const int tid  = threadIdx.x;
    const int w    = tid >> 6;
    const int lane = tid & 63;            // batch b
    const int hl   = blockIdx.x * 4 + w;  // chunk-local h

    const float tau_mem = p_tau_mem[0];
    const float tau_syn = p_tau_syn[0];
    const float target  = p_target[0];
    const float lr      = p_lr[0];
    const float a_mem = (float)exp((double)__fdiv_rn(-0.001f, tau_mem));
    const float a_syn = (float)exp((double)__fdiv_rn(-0.001f, tau_syn));

    float i_syn = 0.0f, v_mem = 0.0f;
    float thr = threshold[h_base + hl];
    float fre = 0.0f;
    unsigned int bits[4] = {0u, 0u, 0u, 0u};

    const int st4 = tid & 3;
    const int sb  = (tid >> 2) & 63;

    for (int tc = 0; tc < 128; tc += 16) {
        __syncthreads();
#pragma unroll
        for (int hh = 0; hh < 4; hh++) {
            const int hg = blockIdx.x * 4 + hh;
            float4 v = *(const float4*)&Wt[(size_t)hg * 8192 + sb * 128 + tc + 4 * st4];
            float* row = &S[(hh * 64 + sb) * 17];
            row[4 * st4 + 0] = v.x;
            row[4 * st4 + 1] = v.y;
            row[4 * st4 + 2] = v.z;
            row[4 * st4 + 3] = v.w;
        }
        __syncthreads();

        const float* row = &S[(w * 64 + lane) * 17];
#pragma unroll
        for (int tt = 0; tt < 16; tt++) {
            const int t = tc + tt;
            const float wv = row[tt];
            i_syn = __fadd_rn(__fmul_rn(a_syn, i_syn), wv);
            v_mem = __fadd_rn(__fmul_rn(a_mem, v_mem), i_syn);
            const bool sp = (v_mem >= thr);
            const unsigned long long mask = __ballot(sp);
            if (sp) v_mem = __fsub_rn(v_mem, thr);
            const int cnt = __popcll(mask);
            const float rate = __fmul_rn((float)cnt, 0.015625f);
            fre = __fadd_rn(__fmul_rn(0.99f, fre), __fmul_rn(0.01f, rate));
            thr = __fadd_rn(thr, __fmul_rn(lr, __fsub_rn(fre, target)));
            if (sp) bits[t >> 5] |= (1u << (t & 31));
        }
    }

    __syncthreads();
    Bits[w][lane][0] = bits[0];
    Bits[w][lane][1] = bits[1];
    Bits[w][lane][2] = bits[2];
    Bits[w][lane][3] = bits[3];
    __syncthreads();

    for (int b = 0; b < 64; b++) {
        const unsigned int word = Bits[w][b][lane >> 4];
        float2 v;
        v.x = ((word >> ((2 * lane) & 31)) & 1u) ? 1.0f : 0.0f;
        v.y = ((word >> ((2 * lane + 1) & 31)) & 1u) ? 1.0f : 0.0f;
        *(float2*)&out[((size_t)b * 2048 + h_base + hl) * 128 + 2 * lane] = v;
    }
}

extern "C" void kernel_launch(void* const* d_in, const int* in_sizes, int n_in,
                              void* d_out, int out_size, void* d_ws, size_t ws_size,
                              hipStream_t stream) {
    const float* spikes    = (const float*)d_in[0];
    const float* weight    = (const float*)d_in[1];
    const float* strength  = (const float*)d_in[2];
    const float* threshold = (const float*)d_in[3];
    const float* tau_mem   = (const float*)d_in[4];
    const float* tau_syn   = (const float*)d_in[5];
    const float* target    = (const float*)d_in[6];
    const float* lr        = (const float*)d_in[7];

    float* out = (float*)d_out;

    // ws: Wt [Hc][8192] f32 + weff [2048][Hc] f32 + bitsT 2 MiB.
    int Hc = 2048;
    while (Hc > 512 && (size_t)Hc * 40960ull + 2097152ull > ws_size) Hc >>= 1;

    float* Wt   = (float*)d_ws;
    float* weff = (float*)d_ws + (size_t)Hc * 8192;
    unsigned char* bitsT = (unsigned char*)(weff + (size_t)2048 * Hc);

    bits_kernel<<<32768, 256, 0, stream>>>(spikes, bitsT);

    for (int hb = 0; hb < 2048; hb += Hc) {
        weff_kernel<<<2048, 256, 0, stream>>>(weight, strength, weff, hb, Hc);
        gemm_kernel<<<dim3(Hc / 512, 256), 256, 0, stream>>>(weff, bitsT, Wt, Hc);
        scan_kernel<<<Hc / 4, 256, 0, stream>>>(
            Wt, threshold, tau_mem, tau_syn, target, lr, out, hb);
    }
}

// Round 10
// 706.722 us; speedup vs baseline: 1.5862x; 1.0155x over previous
//
#include <hip/hip_runtime.h>
#include <math.h>

// B=64, I=K=2048, H=N=2048, T=128.  m = b*128 + t (M=8192).
// Numerics contract (VALIDATED GREEN): Eigen gebp kc=320 K-panels; per C
// element an ascending-k FMA chain within each 320-panel (register
// accumulator), panels combined by UNFUSED f32 adds (beta=0 first).
// Spikes are EXACT 0.0f/1.0f, so fma(1,b,acc)=__fadd_rn(acc,b) and
// fma(0,b,acc)=acc bit-for-bit -> skipping zero-spike terms is bit-exact.
// w_eff = __fmul_rn(weight, strength) rounded once. Scan: f32 state,
// unfused mul/add; exact batch mean via ballot/popcount; correctly-rounded
// expf via (float)exp((double)quotient).
//
// R10 = R9 resubmitted verbatim (R9 bench died to GPU-acquisition timeout,
// no GPU data). Design: R8 inner loop bit-identical; occupancy push.
// KT 16->8 (dbuf 32KB), epilogue Cl 16 m-rows x two passes (33KB), block
// LDS ~34KB + __launch_bounds__(256,3) -> 3 blocks = 12 waves/CU. Same
// kc=320 fold k-boundaries (every 40 tiles of 8; tail kt=255).

__device__ __forceinline__ void async_copy16(const float* g, float* l) {
    __builtin_amdgcn_global_load_lds(
        (const __attribute__((address_space(1))) void*)g,
        (__attribute__((address_space(3))) void*)l, 16, 0, 0);
}

// weff[i][hl] = __fmul_rn(weight[i][h_base+hl], strength[i][h_base+hl])
__global__ __launch_bounds__(256) void weff_kernel(
    const float* __restrict__ weight, const float* __restrict__ strength,
    float* __restrict__ weff, int h_base, int Hc)
{
    const int i = blockIdx.x;  // input row 0..2047
    const float* wr = weight   + (size_t)i * 2048 + h_base;
    const float* sr = strength + (size_t)i * 2048 + h_base;
    float* dr = weff + (size_t)i * Hc;
    for (int c = threadIdx.x * 4; c < Hc; c += 1024) {
        float4 wv = *(const float4*)&wr[c];
        float4 sv = *(const float4*)&sr[c];
        float4 o;
        o.x = __fmul_rn(wv.x, sv.x);
        o.y = __fmul_rn(wv.y, sv.y);
        o.z = __fmul_rn(wv.z, sv.z);
        o.w = __fmul_rn(wv.w, sv.w);
        *(float4*)&dr[c] = o;
    }
}

// bitsT[b][tbyte][k]: bit r = (spikes[b][k][8*tbyte+r] != 0). One wave per
// (b,k): two ballots over 128 t, lanes 0..15 each emit one byte.
__global__ __launch_bounds__(256) void bits_kernel(
    const float* __restrict__ spikes, unsigned char* __restrict__ bitsT)
{
    const int tid  = threadIdx.x;
    const int w    = tid >> 6;
    const int lane = tid & 63;
    const int wid  = blockIdx.x * 4 + w;     // b*2048 + k
    const int b    = wid >> 11;
    const int k    = wid & 2047;
    const float2 v = *(const float2*)&spikes[((size_t)b * 2048 + k) * 128 + 2 * lane];
    const unsigned long long m0 = __ballot(v.x != 0.0f);  // bit l -> t=2l
    const unsigned long long m1 = __ballot(v.y != 0.0f);  // bit l -> t=2l+1
    if (lane < 16) {
        unsigned byte = 0;
#pragma unroll
        for (int q = 0; q < 4; q++) {
            byte |= (unsigned)((m0 >> (4 * lane + q)) & 1ull) << (2 * q);
            byte |= (unsigned)((m1 >> (4 * lane + q)) & 1ull) << (2 * q + 1);
        }
        bitsT[((size_t)b * 16 + lane) * 2048 + k] = (unsigned char)byte;
    }
}

union ShU {
    float Wl[2][8][512];    // 32 KiB: double-buffered weff k-tile (8 k-rows)
    float Cl[16][517];      // 33 KiB: epilogue transpose, 16 m-rows per pass
};

__global__ __launch_bounds__(256, 3) void gemm_kernel(
    const float* __restrict__ weff,          // [2048][Hc]
    const unsigned char* __restrict__ bits,  // [64][16][2048]
    float* __restrict__ Ct,                  // [Hc][M=8192]
    int Hc)
{
    __shared__ ShU sh;

    const int tid  = threadIdx.x;
    const int w    = tid >> 6;          // wave 0..3
    const int lane = tid & 63;
    const int h0   = blockIdx.x * 512;  // chunk-local h-tile
    const int mg   = blockIdx.y;        // 0..255: b = mg>>2, t-quarter = mg&3
    const int b    = mg >> 2;
    const int tq   = mg & 3;
    const int m0g  = b * 128 + tq * 32; // block's first m (32 m per block)
    const int wbyte = (tq << 2) + w;    // wave's t-byte (8 m-rows)

    float acc[8][8];   // acc[r][j]: m-row r, h = h0 + 64*j + lane
    float tot[8][8];   // running unfused panel total
#pragma unroll
    for (int r = 0; r < 8; r++)
#pragma unroll
        for (int j = 0; j < 8; j++) { acc[r][j] = 0.0f; tot[r][j] = 0.0f; }

    const unsigned char* bp = bits + (((size_t)b * 16 + wbyte) << 11);

    // Stage k-tile kt (8 rows x 512 cols = 16 KiB) into buffer buf.
    // Wave w covers rows 2w, 2w+1; each row = 2 KiB as 2 DMA halves.
    auto stageW = [&](int buf, int kt) {
        const int k0 = kt << 3;
        const int r  = w << 1;
#pragma unroll
        for (int i = 0; i < 2; i++) {
            const float* src = &weff[(size_t)(k0 + r + i) * Hc + h0 + (lane << 2)];
            async_copy16(src,       &sh.Wl[buf][r + i][0]);
            async_copy16(src + 256, &sh.Wl[buf][r + i][256]);
        }
    };

#define ROWADD(r) { \
        acc[r][0] = __fadd_rn(acc[r][0], bf[0]); \
        acc[r][1] = __fadd_rn(acc[r][1], bf[1]); \
        acc[r][2] = __fadd_rn(acc[r][2], bf[2]); \
        acc[r][3] = __fadd_rn(acc[r][3], bf[3]); \
        acc[r][4] = __fadd_rn(acc[r][4], bf[4]); \
        acc[r][5] = __fadd_rn(acc[r][5], bf[5]); \
        acc[r][6] = __fadd_rn(acc[r][6], bf[6]); \
        acc[r][7] = __fadd_rn(acc[r][7], bf[7]); }

    uint2 pkv = *(const uint2*)bp;        // bytes for k-tile 0
    stageW(0, 0);
    __syncthreads();                      // prologue drain

    int cur = 0;
    for (int kt = 0; kt < 256; kt++) {
        uint2 pknx = pkv;
        if (kt < 255) {
            stageW(cur ^ 1, kt + 1);      // issue DMA, no wait
            pknx = *(const uint2*)(bp + ((kt + 1) << 3));
        }
        // Force the wave-shared spike bytes into SGPRs -> uniform branches.
        const unsigned w0 = __builtin_amdgcn_readfirstlane(pkv.x);
        const unsigned w1 = __builtin_amdgcn_readfirstlane(pkv.y);

        // Per-lane base; read offsets are compile-time immediates
        // (kk*2048 + j*256 bytes), stride-64-word pairs (read2st64-able).
        const float* wrow = &sh.Wl[cur][0][0] + lane;

#pragma unroll
        for (int kk = 0; kk < 8; kk++) {
            const unsigned word = (kk < 4) ? w0 : w1;
            const unsigned byte = (word >> ((kk & 3) * 8)) & 0xFFu;
            if (byte) {                   // uniform: skip k entirely if no
                float bf[8];              // spike in this wave's 8 m-rows
#pragma unroll
                for (int j = 0; j < 8; j++)
                    bf[j] = wrow[kk * 512 + j * 64];  // 64 consec words: free
                if (byte & 1u)   ROWADD(0)
                if (byte & 2u)   ROWADD(1)
                if (byte & 4u)   ROWADD(2)
                if (byte & 8u)   ROWADD(3)
                if (byte & 16u)  ROWADD(4)
                if (byte & 32u)  ROWADD(5)
                if (byte & 64u)  ROWADD(6)
                if (byte & 128u) ROWADD(7)
            }
        }

        // Eigen kc=320 panel boundary (320 = 40 tiles of 8; tail 128):
        // unfused fold into total, reset chain. Same k boundaries as R8.
        if (((kt + 1) % 40 == 0) || (kt == 255)) {
#pragma unroll
            for (int r = 0; r < 8; r++)
#pragma unroll
                for (int j = 0; j < 8; j++) {
                    tot[r][j] = __fadd_rn(tot[r][j], acc[r][j]);
                    acc[r][j] = 0.0f;
                }
        }

        __syncthreads();   // drains next-tile DMA (landed under compute)
        pkv = pknx;
        cur ^= 1;
    }

    // ---- Epilogue: two passes of 16 m-rows through Cl (Wl dead). ----
    // tot[r][j] is (m = w*8+r, h = j*64+lane). Pass p covers waves 2p,2p+1.
#pragma unroll
    for (int p = 0; p < 2; p++) {
        if ((w >> 1) == p) {
            const int mb = (w & 1) << 3;     // 0 or 8 within the pass tile
#pragma unroll
            for (int r = 0; r < 8; r++)
#pragma unroll
                for (int j = 0; j < 8; j++)
                    sh.Cl[mb + r][j * 64 + lane] = tot[r][j];
        }
        __syncthreads();
        // Store: per u, 64 h-rows x (4-lane group = 64-B contiguous seg).
        const int mq = (tid & 3) << 2;
#pragma unroll
        for (int u = 0; u < 8; u++) {
            const int hr = (u << 6) + (tid >> 2);
            float4 v;
            v.x = sh.Cl[mq + 0][hr];
            v.y = sh.Cl[mq + 1][hr];
            v.z = sh.Cl[mq + 2][hr];
            v.w = sh.Cl[mq + 3][hr];
            *(float4*)&Ct[(size_t)(h0 + hr) * 8192 + m0g + (p << 4) + mq] = v;
        }
        if (p == 0) __syncthreads();
    }
#undef ROWADD
}

// One wave (64 lanes) per h; lane = batch b. Scan state f32, unfused.
// Batch-mean via ballot/popcount (exact). Validated numerics — UNCHANGED
// (verbatim R1 version; Wt layout [Hc][B][T] = [Hc][8192]).
__global__ __launch_bounds__(256) void scan_kernel(
    const float* __restrict__ Wt,          // [Hc][B][T] f32 chunk-local
    const float* __restrict__ threshold,   // [H] f32 global
    const float* __restrict__ p_tau_mem,
    const float* __restrict__ p_tau_syn,
    const float* __restrict__ p_target,
    const float* __restrict__ p_lr,
    float* __restrict__ out,               // [B][H][T] f32 global
    int h_base)
{
    __shared__ float S[4 * 64 * 17];
    __shared__ unsigned int Bits[4][64][4];

    const int tid  = threadIdx.x;
    const int w    = tid >> 6;
    const int lane = tid & 63;            // batch b
    const int hl   = blockIdx.x * 4 + w;  // chunk-local h

    const float tau_mem = p_tau_mem[0];
    const float tau_syn = p_tau_syn[0];
    const float target  = p_target[0];
    const float lr      = p_lr[0];
    const float a_mem = (float)exp((double)__fdiv_rn(-0.001f, tau_mem));
    const float a_syn = (float)exp((double)__fdiv_rn(-0.001f, tau_syn));

    float i_syn = 0.0f, v_mem = 0.0f;
    float thr = threshold[h_base + hl];
    float fre = 0.0f;
    unsigned int bits[4] = {0u, 0u, 0u, 0u};

    const int st4 = tid & 3;
    const int sb  = (tid >> 2) & 63;

    for (int tc = 0; tc < 128; tc += 16) {
        __syncthreads();
#pragma unroll
        for (int hh = 0; hh < 4; hh++) {
            const int hg = blockIdx.x * 4 + hh;
            float4 v = *(const float4*)&Wt[(size_t)hg * 8192 + sb * 128 + tc + 4 * st4];
            float* row = &S[(hh * 64 + sb) * 17];
            row[4 * st4 + 0] = v.x;
            row[4 * st4 + 1] = v.y;
            row[4 * st4 + 2] = v.z;
            row[4 * st4 + 3] = v.w;
        }
        __syncthreads();

        const float* row = &S[(w * 64 + lane) * 17];
#pragma unroll
        for (int tt = 0; tt < 16; tt++) {
            const int t = tc + tt;
            const float wv = row[tt];
            i_syn = __fadd_rn(__fmul_rn(a_syn, i_syn), wv);
            v_mem = __fadd_rn(__fmul_rn(a_mem, v_mem), i_syn);
            const bool sp = (v_mem >= thr);
            const unsigned long long mask = __ballot(sp);
            if (sp) v_mem = __fsub_rn(v_mem, thr);
            const int cnt = __popcll(mask);
            const float rate = __fmul_rn((float)cnt, 0.015625f);
            fre = __fadd_rn(__fmul_rn(0.99f, fre), __fmul_rn(0.01f, rate));
            thr = __fadd_rn(thr, __fmul_rn(lr, __fsub_rn(fre, target)));
            if (sp) bits[t >> 5] |= (1u << (t & 31));
        }
    }

    __syncthreads();
    Bits[w][lane][0] = bits[0];
    Bits[w][lane][1] = bits[1];
    Bits[w][lane][2] = bits[2];
    Bits[w][lane][3] = bits[3];
    __syncthreads();

    for (int b = 0; b < 64; b++) {
        const unsigned int word = Bits[w][b][lane >> 4];
        float2 v;
        v.x = ((word >> ((2 * lane) & 31)) & 1u) ? 1.0f : 0.0f;
        v.y = ((word >> ((2 * lane + 1) & 31)) & 1u) ? 1.0f : 0.0f;
        *(float2*)&out[((size_t)b * 2048 + h_base + hl) * 128 + 2 * lane] = v;
    }
}

extern "C" void kernel_launch(void* const* d_in, const int* in_sizes, int n_in,
                              void* d_out, int out_size, void* d_ws, size_t ws_size,
                              hipStream_t stream) {
    const float* spikes    = (const float*)d_in[0];
    const float* weight    = (const float*)d_in[1];
    const float* strength  = (const float*)d_in[2];
    const float* threshold = (const float*)d_in[3];
    const float* tau_mem   = (const float*)d_in[4];
    const float* tau_syn   = (const float*)d_in[5];
    const float* target    = (const float*)d_in[6];
    const float* lr        = (const float*)d_in[7];

    float* out = (float*)d_out;

    // ws: Wt [Hc][8192] f32 + weff [2048][Hc] f32 + bitsT 2 MiB.
    int Hc = 2048;
    while (Hc > 512 && (size_t)Hc * 40960ull + 2097152ull > ws_size) Hc >>= 1;

    float* Wt   = (float*)d_ws;
    float* weff = (float*)d_ws + (size_t)Hc * 8192;
    unsigned char* bitsT = (unsigned char*)(weff + (size_t)2048 * Hc);

    bits_kernel<<<32768, 256, 0, stream>>>(spikes, bitsT);

    for (int hb = 0; hb < 2048; hb += Hc) {
        weff_kernel<<<2048, 256, 0, stream>>>(weight, strength, weff, hb, Hc);
        gemm_kernel<<<dim3(Hc / 512, 256), 256, 0, stream>>>(weff, bitsT, Wt, Hc);
        scan_kernel<<<Hc / 4, 256, 0, stream>>>(
            Wt, threshold, tau_mem, tau_syn, target, lr, out, hb);
    }
}